// Round 1
// baseline (241.303 us; speedup 1.0000x reference)
//
#include <hip/hip_runtime.h>
#include <hip/hip_bf16.h>

// ---------- types ----------
typedef __attribute__((ext_vector_type(8))) short bf16x8;   // 8 bf16 in 4 VGPRs
typedef __attribute__((ext_vector_type(4))) short bf16x4;   // 4 bf16 in 2 VGPRs
typedef __attribute__((ext_vector_type(4))) float f32x4;

#define LOG2E 1.4426950408889634f

// fp32 -> bf16 round-to-nearest-even (no NaN expected in this data)
__device__ __forceinline__ short f2bf(float f) {
    union { float f; unsigned u; } v; v.f = f;
    unsigned r = v.u + 0x7fff + ((v.u >> 16) & 1);
    return (short)(r >> 16);
}

// ---------- sizes ----------
#define BB 4
#define TT 4096
#define CC 1024
#define HD 64

// =====================================================================
// Kernel 1: pack W q/k/v (fp32 [1024][64]) -> transposed bf16 Wt[192][1024]
// Wt[n][k] = W_{n/64}[k][n%64]
// =====================================================================
__global__ void prep_w(const float* __restrict__ Wq, const float* __restrict__ Wk,
                       const float* __restrict__ Wv, short* __restrict__ Wt) {
    const int n = blockIdx.x;                 // 0..191
    const float* W = (n < 64) ? Wq : (n < 128) ? Wk : Wv;
    const int col = n & 63;
    for (int k = threadIdx.x; k < CC; k += blockDim.x)
        Wt[n * CC + k] = f2bf(W[k * HD + col]);
}

// =====================================================================
// Kernel 2: QKV projection. Block = 64 rows of x, 4 waves (each 16 rows).
// Q,K stored row-major bf16 [B*T][64]; V stored transposed Vt[B][64][T].
// =====================================================================
__global__ __launch_bounds__(256) void proj_qkv(const float* __restrict__ x,
        const short* __restrict__ Wt, short* __restrict__ Q,
        short* __restrict__ K, short* __restrict__ Vt) {
    __shared__ short xs[64 * 72];     // x tile, bf16, row pad 72 (bank-conflict-free)
    __shared__ short ws[192 * 72];    // W chunk, bf16

    const int tid  = threadIdx.x;
    const int lane = tid & 63;
    const int wv   = tid >> 6;        // wave 0..3
    const int lm   = lane & 15;
    const int lg   = lane >> 4;
    const int mbase = blockIdx.x * 64;

    f32x4 acc[12];
    #pragma unroll
    for (int i = 0; i < 12; ++i) acc[i] = f32x4{0.f, 0.f, 0.f, 0.f};

    for (int kc = 0; kc < 16; ++kc) {
        // ---- stage x chunk [64 rows][64 k] fp32->bf16 ----
        {
            const int r0 = tid >> 4;          // 0..15
            const int q4 = tid & 15;          // which float4 in the row
            #pragma unroll
            for (int rr = 0; rr < 4; ++rr) {
                const int r = rr * 16 + r0;
                float4 xv = reinterpret_cast<const float4*>(
                    x + (size_t)(mbase + r) * CC + kc * 64)[q4];
                bf16x4 b;
                b[0] = f2bf(xv.x); b[1] = f2bf(xv.y);
                b[2] = f2bf(xv.z); b[3] = f2bf(xv.w);
                *reinterpret_cast<bf16x4*>(&xs[r * 72 + q4 * 4]) = b;
            }
        }
        // ---- stage W chunk [192 rows][64 k] ----
        {
            #pragma unroll
            for (int it = 0; it < 6; ++it) {
                const int idx = it * 256 + tid;      // 0..1535
                const int n  = idx >> 3;
                const int c8 = idx & 7;
                bf16x8 w8 = *reinterpret_cast<const bf16x8*>(
                    Wt + n * CC + kc * 64 + c8 * 8);
                *reinterpret_cast<bf16x8*>(&ws[n * 72 + c8 * 8]) = w8;
            }
        }
        __syncthreads();

        // ---- MFMA: wave wv owns rows [wv*16, wv*16+16), all 12 n-chunks ----
        bf16x8 a0 = *reinterpret_cast<const bf16x8*>(&xs[(wv * 16 + lm) * 72 + lg * 8]);
        bf16x8 a1 = *reinterpret_cast<const bf16x8*>(&xs[(wv * 16 + lm) * 72 + 32 + lg * 8]);
        #pragma unroll
        for (int c = 0; c < 12; ++c) {
            bf16x8 b0 = *reinterpret_cast<const bf16x8*>(&ws[(c * 16 + lm) * 72 + lg * 8]);
            bf16x8 b1 = *reinterpret_cast<const bf16x8*>(&ws[(c * 16 + lm) * 72 + 32 + lg * 8]);
            acc[c] = __builtin_amdgcn_mfma_f32_16x16x32_bf16(a0, b0, acc[c], 0, 0, 0);
            acc[c] = __builtin_amdgcn_mfma_f32_16x16x32_bf16(a1, b1, acc[c], 0, 0, 0);
        }
        __syncthreads();
    }

    // ---- store: D layout col = lane&15, row = (lane>>4)*4 + reg ----
    const int mrow = mbase + wv * 16 + lg * 4;
    #pragma unroll
    for (int c = 0; c < 4; ++c) {
        #pragma unroll
        for (int r = 0; r < 4; ++r) {
            Q[(size_t)(mrow + r) * HD + c * 16 + lm] = f2bf(acc[c][r]);
            K[(size_t)(mrow + r) * HD + c * 16 + lm] = f2bf(acc[c + 4][r]);
        }
    }
    // V transposed: Vt[b][d][t]
    const int bb   = mbase >> 12;               // /4096
    const int tloc = (mbase & 4095) + wv * 16 + lg * 4;
    #pragma unroll
    for (int c = 0; c < 4; ++c) {
        bf16x4 v4;
        #pragma unroll
        for (int r = 0; r < 4; ++r) v4[r] = f2bf(acc[c + 8][r]);
        *reinterpret_cast<bf16x4*>(
            Vt + (size_t)bb * (HD * TT) + (size_t)(c * 16 + lm) * TT + tloc) = v4;
    }
}

// =====================================================================
// Kernel 3: causal flash attention, per-wave 16-row q-tile, KV tiles of 32.
// Balanced: block j (per batch) handles q-tiles {j, 127-j, 128+j, 255-j}.
// =====================================================================
__global__ __launch_bounds__(256) void attn(const short* __restrict__ Q,
        const short* __restrict__ K, const short* __restrict__ Vt,
        float* __restrict__ out) {
    __shared__ short p_lds[4][16 * 40];   // per-wave P tile (16 x 32, stride 40)

    const int tid  = threadIdx.x;
    const int lane = tid & 63;
    const int wv   = tid >> 6;
    const int lm   = lane & 15;
    const int lg   = lane >> 4;

    const int b = blockIdx.x >> 6;        // batch
    const int j = blockIdx.x & 63;
    int qtile;
    switch (wv) {
        case 0:  qtile = j;        break;
        case 1:  qtile = 127 - j;  break;
        case 2:  qtile = 128 + j;  break;
        default: qtile = 255 + 0 - j; break;
    }
    const int qbase = qtile * 16;
    const size_t qkb = (size_t)b * TT * HD;      // Q/K batch base (elements)
    const size_t vtb = (size_t)b * HD * TT;      // Vt batch base

    // Q fragments (A-operand): lane: row=lm, k = lg*8 + i (+32 for second)
    bf16x8 qf0 = *reinterpret_cast<const bf16x8*>(Q + qkb + (size_t)(qbase + lm) * HD + lg * 8);
    bf16x8 qf1 = *reinterpret_cast<const bf16x8*>(Q + qkb + (size_t)(qbase + lm) * HD + 32 + lg * 8);

    f32x4 o[4];
    #pragma unroll
    for (int c = 0; c < 4; ++c) o[c] = f32x4{0.f, 0.f, 0.f, 0.f};
    float mrun[4], lrun[4];
    #pragma unroll
    for (int r = 0; r < 4; ++r) { mrun[r] = -1e30f; lrun[r] = 0.f; }

    short* pl = &p_lds[wv][0];
    const int niter = (qtile >> 1) + 1;

    for (int it = 0; it < niter; ++it) {
        const int kv = it * 32;
        // ---- QK^T: S (16 x 32) = Q (16x64) . K^T ----
        f32x4 s0 = f32x4{0.f, 0.f, 0.f, 0.f};
        f32x4 s1 = f32x4{0.f, 0.f, 0.f, 0.f};
        {
            bf16x8 k00 = *reinterpret_cast<const bf16x8*>(K + qkb + (size_t)(kv + lm) * HD + lg * 8);
            bf16x8 k01 = *reinterpret_cast<const bf16x8*>(K + qkb + (size_t)(kv + lm) * HD + 32 + lg * 8);
            bf16x8 k10 = *reinterpret_cast<const bf16x8*>(K + qkb + (size_t)(kv + 16 + lm) * HD + lg * 8);
            bf16x8 k11 = *reinterpret_cast<const bf16x8*>(K + qkb + (size_t)(kv + 16 + lm) * HD + 32 + lg * 8);
            s0 = __builtin_amdgcn_mfma_f32_16x16x32_bf16(qf0, k00, s0, 0, 0, 0);
            s0 = __builtin_amdgcn_mfma_f32_16x16x32_bf16(qf1, k01, s0, 0, 0, 0);
            s1 = __builtin_amdgcn_mfma_f32_16x16x32_bf16(qf0, k10, s1, 0, 0, 0);
            s1 = __builtin_amdgcn_mfma_f32_16x16x32_bf16(qf1, k11, s1, 0, 0, 0);
        }
        // ---- scale + causal mask ----
        float sv0[4], sv1[4];
        #pragma unroll
        for (int r = 0; r < 4; ++r) { sv0[r] = s0[r] * 0.125f; sv1[r] = s1[r] * 0.125f; }
        if (kv + 31 > qbase) {
            #pragma unroll
            for (int r = 0; r < 4; ++r) {
                const int m_g = qbase + lg * 4 + r;
                if (kv + lm > m_g)      sv0[r] = -1e30f;
                if (kv + 16 + lm > m_g) sv1[r] = -1e30f;
            }
        }
        // ---- online softmax (rows live in 16-lane groups) ----
        float alpha[4];
        #pragma unroll
        for (int r = 0; r < 4; ++r) {
            float v = fmaxf(sv0[r], sv1[r]);
            v = fmaxf(v, __shfl_xor(v, 1));
            v = fmaxf(v, __shfl_xor(v, 2));
            v = fmaxf(v, __shfl_xor(v, 4));
            v = fmaxf(v, __shfl_xor(v, 8));
            const float mnew = fmaxf(mrun[r], v);
            alpha[r] = exp2f((mrun[r] - mnew) * LOG2E);
            mrun[r] = mnew;
            const float p0 = exp2f((sv0[r] - mnew) * LOG2E);
            const float p1 = exp2f((sv1[r] - mnew) * LOG2E);
            pl[(lg * 4 + r) * 40 + lm]      = f2bf(p0);
            pl[(lg * 4 + r) * 40 + 16 + lm] = f2bf(p1);
            float rs = p0 + p1;
            rs += __shfl_xor(rs, 1);
            rs += __shfl_xor(rs, 2);
            rs += __shfl_xor(rs, 4);
            rs += __shfl_xor(rs, 8);
            lrun[r] = lrun[r] * alpha[r] + rs;
        }
        // wave-local LDS transpose fence (no __syncthreads: waves diverge!)
        asm volatile("s_waitcnt lgkmcnt(0)" ::: "memory");
        // ---- PV: O += P (16x32) . V (32x64) ----
        bf16x8 pa = *reinterpret_cast<const bf16x8*>(&pl[lm * 40 + lg * 8]);
        #pragma unroll
        for (int c = 0; c < 4; ++c) {
            bf16x8 vb = *reinterpret_cast<const bf16x8*>(
                Vt + vtb + (size_t)(c * 16 + lm) * TT + kv + lg * 8);
            f32x4 t = o[c];
            #pragma unroll
            for (int r = 0; r < 4; ++r) t[r] *= alpha[r];
            o[c] = __builtin_amdgcn_mfma_f32_16x16x32_bf16(pa, vb, t, 0, 0, 0);
        }
    }

    // ---- epilogue: normalize + store fp32 ----
    #pragma unroll
    for (int r = 0; r < 4; ++r) {
        const float inv = 1.0f / lrun[r];
        #pragma unroll
        for (int c = 0; c < 4; ++c)
            out[qkb + (size_t)(qbase + lg * 4 + r) * HD + c * 16 + lm] = o[c][r] * inv;
    }
}

// =====================================================================
extern "C" void kernel_launch(void* const* d_in, const int* in_sizes, int n_in,
                              void* d_out, int out_size, void* d_ws, size_t ws_size,
                              hipStream_t stream) {
    const float* x  = (const float*)d_in[0];
    const float* Wq = (const float*)d_in[1];
    const float* Wk = (const float*)d_in[2];
    const float* Wv = (const float*)d_in[3];
    float* out = (float*)d_out;

    char* ws = (char*)d_ws;
    short* Wt = (short*)(ws);                                   // 192*1024*2   = 393216 B
    short* Q  = (short*)(ws + 393216);                          // 16384*64*2   = 2097152 B
    short* K  = (short*)(ws + 393216 + 2097152);                // 2097152 B
    short* Vt = (short*)(ws + 393216 + 2 * 2097152);            // 2097152 B

    hipLaunchKernelGGL(prep_w,   dim3(192), dim3(256), 0, stream, Wq, Wk, Wv, Wt);
    hipLaunchKernelGGL(proj_qkv, dim3(256), dim3(256), 0, stream, x, Wt, Q, K, Vt);
    hipLaunchKernelGGL(attn,     dim3(256), dim3(256), 0, stream, Q, K, Vt, out);
}

// Round 2
// 125.588 us; speedup vs baseline: 1.9214x; 1.9214x over previous
//
#include <hip/hip_runtime.h>
#include <hip/hip_bf16.h>

// ---------- types ----------
typedef __attribute__((ext_vector_type(8))) short bf16x8;   // 8 bf16 in 4 VGPRs
typedef __attribute__((ext_vector_type(4))) short bf16x4;   // 4 bf16 in 2 VGPRs
typedef __attribute__((ext_vector_type(4))) float f32x4;

#define LOG2E 1.4426950408889634f

// fp32 -> bf16 round-to-nearest-even
__device__ __forceinline__ short f2bf(float f) {
    union { float f; unsigned u; } v; v.f = f;
    unsigned r = v.u + 0x7fff + ((v.u >> 16) & 1);
    return (short)(r >> 16);
}

// ---------- sizes ----------
#define BB 4
#define TT 4096
#define CC 1024
#define HD 64
#define NSEG 4

// =====================================================================
// Kernel 1: pack W q/k/v (fp32 [1024][64]) -> transposed bf16 Wt[192][1024]
// =====================================================================
__global__ void prep_w(const float* __restrict__ Wq, const float* __restrict__ Wk,
                       const float* __restrict__ Wv, short* __restrict__ Wt) {
    const int n = blockIdx.x;                 // 0..191
    const float* W = (n < 64) ? Wq : (n < 128) ? Wk : Wv;
    const int col = n & 63;
    for (int k = threadIdx.x; k < CC; k += blockDim.x)
        Wt[n * CC + k] = f2bf(W[k * HD + col]);
}

// =====================================================================
// Kernel 2: QKV projection. Block = 32 rows of x, 8 waves.
// Wave wv: rows (wv&1)*16..+16 of the tile, n-chunks (wv>>1)*3..+3.
// Q,K row-major bf16 [B*T][64]; V transposed Vt[B][64][T].
// =====================================================================
__global__ __launch_bounds__(512) void proj_qkv(const float* __restrict__ x,
        const short* __restrict__ Wt, short* __restrict__ Q,
        short* __restrict__ K, short* __restrict__ Vt) {
    __shared__ short xs[32 * 72];     // x tile bf16, pad-72
    __shared__ short wsm[192 * 72];   // W chunk bf16

    const int tid  = threadIdx.x;
    const int lane = tid & 63;
    const int wv   = tid >> 6;        // 0..7
    const int lm   = lane & 15;
    const int lg   = lane >> 4;
    const int mhalf = wv & 1;
    const int ngrp  = wv >> 1;        // 0..3  -> chunks ngrp*3..+3
    const int mbase = blockIdx.x * 32;

    f32x4 acc[3];
    #pragma unroll
    for (int i = 0; i < 3; ++i) acc[i] = f32x4{0.f, 0.f, 0.f, 0.f};

    for (int kc = 0; kc < 16; ++kc) {
        // ---- stage x chunk [32 rows][64 k] fp32->bf16 (one float4/thread) ----
        {
            const int r  = tid >> 4;          // 0..31
            const int q4 = tid & 15;
            float4 xv = reinterpret_cast<const float4*>(
                x + (size_t)(mbase + r) * CC + kc * 64)[q4];
            bf16x4 b;
            b[0] = f2bf(xv.x); b[1] = f2bf(xv.y);
            b[2] = f2bf(xv.z); b[3] = f2bf(xv.w);
            *reinterpret_cast<bf16x4*>(&xs[r * 72 + q4 * 4]) = b;
        }
        // ---- stage W chunk [192 rows][64 k], diagonal perm on c8 ----
        {
            #pragma unroll
            for (int it = 0; it < 3; ++it) {
                const int idx = it * 512 + tid;       // 0..1535
                const int n   = idx >> 3;
                const int c8  = ((idx & 7) + n) & 7;  // diagonal: de-conflict banks
                bf16x8 w8 = *reinterpret_cast<const bf16x8*>(
                    Wt + n * CC + kc * 64 + c8 * 8);
                *reinterpret_cast<bf16x8*>(&wsm[n * 72 + c8 * 8]) = w8;
            }
        }
        __syncthreads();

        bf16x8 a0 = *reinterpret_cast<const bf16x8*>(&xs[(mhalf * 16 + lm) * 72 + lg * 8]);
        bf16x8 a1 = *reinterpret_cast<const bf16x8*>(&xs[(mhalf * 16 + lm) * 72 + 32 + lg * 8]);
        #pragma unroll
        for (int c = 0; c < 3; ++c) {
            const int cn = ngrp * 3 + c;
            bf16x8 b0 = *reinterpret_cast<const bf16x8*>(&wsm[(cn * 16 + lm) * 72 + lg * 8]);
            bf16x8 b1 = *reinterpret_cast<const bf16x8*>(&wsm[(cn * 16 + lm) * 72 + 32 + lg * 8]);
            acc[c] = __builtin_amdgcn_mfma_f32_16x16x32_bf16(a0, b0, acc[c], 0, 0, 0);
            acc[c] = __builtin_amdgcn_mfma_f32_16x16x32_bf16(a1, b1, acc[c], 0, 0, 0);
        }
        __syncthreads();
    }

    // ---- store: D layout col = lane&15, row = lg*4 + reg ----
    const int mrow = mbase + mhalf * 16 + lg * 4;
    #pragma unroll
    for (int c = 0; c < 3; ++c) {
        const int cn = ngrp * 3 + c;
        if (cn < 4) {
            #pragma unroll
            for (int r = 0; r < 4; ++r)
                Q[(size_t)(mrow + r) * HD + cn * 16 + lm] = f2bf(acc[c][r]);
        } else if (cn < 8) {
            #pragma unroll
            for (int r = 0; r < 4; ++r)
                K[(size_t)(mrow + r) * HD + (cn - 4) * 16 + lm] = f2bf(acc[c][r]);
        } else {
            const int bb   = mbase >> 12;
            const int tloc = (mbase & 4095) + mhalf * 16 + lg * 4;
            bf16x4 v4;
            #pragma unroll
            for (int r = 0; r < 4; ++r) v4[r] = f2bf(acc[c][r]);
            *reinterpret_cast<bf16x4*>(
                Vt + (size_t)bb * (HD * TT) + (size_t)((cn - 8) * 16 + lm) * TT + tloc) = v4;
        }
    }
}

// =====================================================================
// Kernel 3: causal flash attention, split-KV (4 segments per q-tile).
// Block = 4 waves = 4 segments of one (b, qtile). Writes unnormalized
// partials (O, m, l) to workspace.
// =====================================================================
__global__ __launch_bounds__(256) void attn(const short* __restrict__ Q,
        const short* __restrict__ K, const short* __restrict__ Vt,
        float* __restrict__ Opart, float* __restrict__ Mpart,
        float* __restrict__ Lpart) {
    __shared__ short p_lds[4][16 * 40];   // per-wave P tile (16 x 32, stride 40)

    const int tid  = threadIdx.x;
    const int lane = tid & 63;
    const int wv   = tid >> 6;            // segment
    const int lm   = lane & 15;
    const int lg   = lane >> 4;

    const int j    = blockIdx.x & 255;
    const int b    = blockIdx.x >> 8;
    const int qtile = ((j * 67) + (b << 6)) & 255;   // spread heavy tiles over CUs
    const int seg  = wv;

    const int qbase = qtile * 16;
    const size_t qkb = (size_t)b * TT * HD;
    const size_t vtb = (size_t)b * HD * TT;

    const int niter = (qtile >> 1) + 1;
    const int chunk = (niter + NSEG - 1) >> 2;
    const int it0 = seg * chunk;
    const int it1 = min(it0 + chunk, niter);

    // Q fragments (A-operand): row=lm, k = lg*8 + i (+32 for second)
    bf16x8 qf0 = *reinterpret_cast<const bf16x8*>(Q + qkb + (size_t)(qbase + lm) * HD + lg * 8);
    bf16x8 qf1 = *reinterpret_cast<const bf16x8*>(Q + qkb + (size_t)(qbase + lm) * HD + 32 + lg * 8);

    f32x4 o[4];
    #pragma unroll
    for (int c = 0; c < 4; ++c) o[c] = f32x4{0.f, 0.f, 0.f, 0.f};
    float mrun[4], lrun[4];
    #pragma unroll
    for (int r = 0; r < 4; ++r) { mrun[r] = -1e30f; lrun[r] = 0.f; }

    short* pl = &p_lds[wv][0];

    for (int it = it0; it < it1; ++it) {
        const int kv = it * 32;
        // ---- QK^T ----
        f32x4 s0 = f32x4{0.f, 0.f, 0.f, 0.f};
        f32x4 s1 = f32x4{0.f, 0.f, 0.f, 0.f};
        {
            bf16x8 k00 = *reinterpret_cast<const bf16x8*>(K + qkb + (size_t)(kv + lm) * HD + lg * 8);
            bf16x8 k01 = *reinterpret_cast<const bf16x8*>(K + qkb + (size_t)(kv + lm) * HD + 32 + lg * 8);
            bf16x8 k10 = *reinterpret_cast<const bf16x8*>(K + qkb + (size_t)(kv + 16 + lm) * HD + lg * 8);
            bf16x8 k11 = *reinterpret_cast<const bf16x8*>(K + qkb + (size_t)(kv + 16 + lm) * HD + 32 + lg * 8);
            s0 = __builtin_amdgcn_mfma_f32_16x16x32_bf16(qf0, k00, s0, 0, 0, 0);
            s0 = __builtin_amdgcn_mfma_f32_16x16x32_bf16(qf1, k01, s0, 0, 0, 0);
            s1 = __builtin_amdgcn_mfma_f32_16x16x32_bf16(qf0, k10, s1, 0, 0, 0);
            s1 = __builtin_amdgcn_mfma_f32_16x16x32_bf16(qf1, k11, s1, 0, 0, 0);
        }
        // ---- prefetch V (overlaps softmax) ----
        bf16x8 vb[4];
        #pragma unroll
        for (int c = 0; c < 4; ++c)
            vb[c] = *reinterpret_cast<const bf16x8*>(
                Vt + vtb + (size_t)(c * 16 + lm) * TT + kv + lg * 8);
        // ---- scale + causal mask ----
        float sv0[4], sv1[4];
        #pragma unroll
        for (int r = 0; r < 4; ++r) { sv0[r] = s0[r] * 0.125f; sv1[r] = s1[r] * 0.125f; }
        if (kv + 31 > qbase) {
            #pragma unroll
            for (int r = 0; r < 4; ++r) {
                const int m_g = qbase + lg * 4 + r;
                if (kv + lm > m_g)      sv0[r] = -1e30f;
                if (kv + 16 + lm > m_g) sv1[r] = -1e30f;
            }
        }
        // ---- online softmax (rows live in 16-lane groups) ----
        float alpha[4];
        #pragma unroll
        for (int r = 0; r < 4; ++r) {
            float v = fmaxf(sv0[r], sv1[r]);
            v = fmaxf(v, __shfl_xor(v, 1));
            v = fmaxf(v, __shfl_xor(v, 2));
            v = fmaxf(v, __shfl_xor(v, 4));
            v = fmaxf(v, __shfl_xor(v, 8));
            const float mnew = fmaxf(mrun[r], v);
            alpha[r] = __builtin_amdgcn_exp2f((mrun[r] - mnew) * LOG2E);
            mrun[r] = mnew;
            const float p0 = __builtin_amdgcn_exp2f((sv0[r] - mnew) * LOG2E);
            const float p1 = __builtin_amdgcn_exp2f((sv1[r] - mnew) * LOG2E);
            pl[(lg * 4 + r) * 40 + lm]      = f2bf(p0);
            pl[(lg * 4 + r) * 40 + 16 + lm] = f2bf(p1);
            float rs = p0 + p1;
            rs += __shfl_xor(rs, 1);
            rs += __shfl_xor(rs, 2);
            rs += __shfl_xor(rs, 4);
            rs += __shfl_xor(rs, 8);
            lrun[r] = lrun[r] * alpha[r] + rs;
        }
        // wave-local LDS fence (waves are independent: no __syncthreads)
        asm volatile("s_waitcnt lgkmcnt(0)" ::: "memory");
        // ---- PV: O += P (16x32) . V (32x64) ----
        bf16x8 pa = *reinterpret_cast<const bf16x8*>(&pl[lm * 40 + lg * 8]);
        #pragma unroll
        for (int c = 0; c < 4; ++c) {
            f32x4 t = o[c];
            #pragma unroll
            for (int r = 0; r < 4; ++r) t[r] *= alpha[r];
            o[c] = __builtin_amdgcn_mfma_f32_16x16x32_bf16(pa, vb[c], t, 0, 0, 0);
        }
    }

    // ---- write unnormalized partials ----
    const int task = (((b << 8) + qtile) << 2) + seg;
    float* Ob = Opart + (size_t)task * (16 * HD);
    #pragma unroll
    for (int c = 0; c < 4; ++c)
        #pragma unroll
        for (int r = 0; r < 4; ++r)
            Ob[(lg * 4 + r) * HD + c * 16 + lm] = o[c][r];
    if (lm == 0) {
        #pragma unroll
        for (int r = 0; r < 4; ++r) {
            Mpart[task * 16 + lg * 4 + r] = mrun[r];
            Lpart[task * 16 + lg * 4 + r] = lrun[r];
        }
    }
}

// =====================================================================
// Kernel 4: combine split-KV partials -> final fp32 output
// =====================================================================
__global__ __launch_bounds__(256) void combine(const float* __restrict__ Opart,
        const float* __restrict__ Mpart, const float* __restrict__ Lpart,
        float* __restrict__ out) {
    const int tid  = threadIdx.x;
    const int lane = tid & 63;
    const int wv   = tid >> 6;
    const int bq   = blockIdx.x * 4 + wv;     // 0..1023
    const int b    = bq >> 8;
    const int qtile = bq & 255;
    const int t0   = bq << 2;                 // first task

    #pragma unroll 4
    for (int r = 0; r < 16; ++r) {
        float ms[NSEG];
        float mmax = -1e30f;
        #pragma unroll
        for (int s = 0; s < NSEG; ++s) {
            ms[s] = Mpart[(t0 + s) * 16 + r];
            mmax = fmaxf(mmax, ms[s]);
        }
        float lsum = 0.f, acc = 0.f;
        #pragma unroll
        for (int s = 0; s < NSEG; ++s) {
            const float w = __builtin_amdgcn_exp2f((ms[s] - mmax) * LOG2E);
            lsum += Lpart[(t0 + s) * 16 + r] * w;
            acc  += Opart[((size_t)(t0 + s) * 16 + r) * HD + lane] * w;
        }
        out[((size_t)b * TT + qtile * 16 + r) * HD + lane] = acc / lsum;
    }
}

// =====================================================================
extern "C" void kernel_launch(void* const* d_in, const int* in_sizes, int n_in,
                              void* d_out, int out_size, void* d_ws, size_t ws_size,
                              hipStream_t stream) {
    const float* x  = (const float*)d_in[0];
    const float* Wq = (const float*)d_in[1];
    const float* Wk = (const float*)d_in[2];
    const float* Wv = (const float*)d_in[3];
    float* out = (float*)d_out;

    char* ws = (char*)d_ws;
    short* Wt = (short*)(ws);                                   // 393216 B
    short* Q  = (short*)(ws + 393216);                          // 2097152 B
    short* K  = (short*)(ws + 393216 + 2097152);                // 2097152 B
    short* Vt = (short*)(ws + 393216 + 2 * 2097152);            // 2097152 B
    float* Opart = (float*)(ws + 6684672);                      // 4096*16*64*4 = 16777216 B
    float* Mpart = (float*)(ws + 6684672 + 16777216);           // 262144 B
    float* Lpart = (float*)(ws + 6684672 + 16777216 + 262144);  // 262144 B
    // total: 23986176 B (~23 MiB)

    hipLaunchKernelGGL(prep_w,   dim3(192),  dim3(256), 0, stream, Wq, Wk, Wv, Wt);
    hipLaunchKernelGGL(proj_qkv, dim3(512),  dim3(512), 0, stream, x, Wt, Q, K, Vt);
    hipLaunchKernelGGL(attn,     dim3(1024), dim3(256), 0, stream, Q, K, Vt,
                       Opart, Mpart, Lpart);
    hipLaunchKernelGGL(combine,  dim3(256),  dim3(256), 0, stream,
                       Opart, Mpart, Lpart, out);
}